// Round 16
// baseline (4009.995 us; speedup 1.0000x reference)
//
#include <hip/hip_runtime.h>

#define T_STEPS 4096
#define BATCH   64
#define NB      16            // batch elements per block
#define INDIM   4
#define H       256
#define OUTD    2
#define CHUNK   32

typedef __fp16 v8h    __attribute__((ext_vector_type(8)));
typedef float  f32x4  __attribute__((ext_vector_type(4)));
typedef unsigned int u32x4 __attribute__((ext_vector_type(4)));

__device__ __forceinline__ unsigned int pk(float a, float b) {
    return __builtin_bit_cast(unsigned int, __builtin_amdgcn_cvt_pkrtz(a, b));
}

__device__ __forceinline__ float fast_tanh(float x) {
    float ax = fabsf(x);
    float e  = __expf(-2.0f * ax);
    float r  = (1.0f - e) * __builtin_amdgcn_rcpf(1.0f + e);
    return copysignf(r, x);
}

// 256 threads = 4 waves = 1 wave/SIMD; waves_per_eu(1,1) -> big reg budget.
// R15 taught: MFMA D and C must be in the SAME register file. R16 chain:
// A from pinned AGPRs (Wh resident, zero per-step reload), B from VGPR
// (ds_read), C/D in VGPR throughout (always-legal encoding).
// Hazards: entry s_nop 2 (VALU->MFMA read); body = SrcC-forwarded
// accumulate (0 nops); exit s_nop 7 + s_nop 1 (MFMA D -> VALU read).
__global__ __attribute__((amdgpu_waves_per_eu(1, 1))) __launch_bounds__(256)
void elman_kernel(const float* __restrict__ input,
                  const float* __restrict__ Wi,
                  const float* __restrict__ bi,
                  const float* __restrict__ Wh,
                  const float* __restrict__ bh,
                  const float* __restrict__ Wf,
                  const float* __restrict__ bf,
                  float* __restrict__ out)
{
    const int b0 = blockIdx.x * NB;
    const int t  = threadIdx.x;
    const int w  = t >> 6;          // wave: M rows 64w..64w+63
    const int l  = t & 63;
    const int qD = l >> 4;          // quad
    const int n  = l & 15;          // batch col
    const int is_q0 = (qD == 0);

    __shared__ u32x4 Bb[2][8][64];      // h as B-fragments, ping-pong (16 KB)
    __shared__ uint2 Xs[CHUNK][16];     // staged x, f16 (4 KB)
    __shared__ float Hp[2][32][4];      // head partials [buf][o*16+n][w]
    __shared__ float Obx[CHUNK][32];    // finalized outputs (4 KB)
    __shared__ float Dump[64];

    // ---- A fragments (layout verified R13): m=lane&15, k=quad*8+j ----
    u32x4 AfA[4][8];                    // kk 0..7 -> pinned in AGPRs
    u32x4 Af8[4];                       // 9th kstep [Wi | bias] -> VGPR
    #pragma unroll
    for (int s = 0; s < 4; ++s) {
        const int m = 64 * w + 16 * s + n;
        #pragma unroll
        for (int kk = 0; kk < 8; ++kk) {
            const float* ap = Wh + (size_t)m * H + kk * 32 + qD * 8;
            float4 u0 = *(const float4*)ap;
            float4 u1 = *(const float4*)(ap + 4);
            AfA[s][kk] = (u32x4){pk(u0.x, u0.y), pk(u0.z, u0.w),
                                 pk(u1.x, u1.y), pk(u1.z, u1.w)};
        }
        if (is_q0) {
            float4 wiv  = *(const float4*)(Wi + m * INDIM);
            float  bias = bi[m] + bh[m];
            Af8[s] = (u32x4){pk(wiv.x, wiv.y), pk(wiv.z, wiv.w),
                             pk(bias, 0.0f), 0u};
        } else {
            Af8[s] = (u32x4){0u, 0u, 0u, 0u};
        }
    }
    #pragma unroll
    for (int s = 0; s < 4; ++s)
        #pragma unroll
        for (int kk = 0; kk < 8; ++kk)
            asm volatile("" : "+a"(AfA[s][kk]));    // force AGPR residency

    // head weights for my 16 rows (k = 64w + 16s + 4qD + r)
    float wf0[16], wf1[16];
    #pragma unroll
    for (int s = 0; s < 4; ++s)
        #pragma unroll
        for (int r = 0; r < 4; ++r) {
            const int k = 64 * w + 16 * s + 4 * qD + r;
            wf0[s * 4 + r] = Wf[k];
            wf1[s * 4 + r] = Wf[H + k];
        }
    const float bf0 = bf[0], bf1 = bf[1];

    for (int idx = t; idx < 1024; idx += 256)      // h0 = 0 (both buffers)
        ((u32x4*)Bb)[idx] = (u32x4){0u, 0u, 0u, 0u};
    __syncthreads();

    const f32x4 zq = {0.f, 0.f, 0.f, 0.f};

    for (int chunk = 0; chunk < T_STEPS / CHUNK; ++chunk) {
        // ---- stage this chunk's x as f16 ----
        for (int idx = t; idx < CHUNK * 16; idx += 256) {
            const int i = idx >> 4, nn = idx & 15;
            const int ta = chunk * CHUNK + i;
            float4 xv = *(const float4*)(input + ((size_t)ta * BATCH + b0 + nn) * INDIM);
            Xs[i][nn] = make_uint2(pk(xv.x, xv.y), pk(xv.z, xv.w));
        }
        __syncthreads();

        #pragma unroll 1
        for (int i = 0; i < CHUNK; ++i) {
            const int step = chunk * CHUNK + i;
            const int rb = step & 1, wb = rb ^ 1;

            // wave0: finalize previous step's output (within-chunk)
            if (w == 0 && l < 32 && i > 0) {
                f32x4 h4 = *(const f32x4*)&Hp[wb][l][0];
                float o  = h4.x + h4.y + h4.z + h4.w + ((l >> 4) ? bf1 : bf0);
                Obx[i - 1][l] = fast_tanh(o);
            }

            // B fragments of h
            u32x4 bfu[8];
            #pragma unroll
            for (int kk = 0; kk < 8; ++kk) bfu[kk] = Bb[rb][kk][l];
            // 9th kstep: [x_t ; 1]
            uint2 xr = Xs[i][n];
            u32x4 b9u;
            b9u.x = is_q0 ? xr.x : 0u;
            b9u.y = is_q0 ? xr.y : 0u;
            b9u.z = is_q0 ? 0x00003C00u : 0u;   // f16 1.0 at k=4
            b9u.w = 0u;

            // ---- full-asm MFMA chains, acc in VGPR (D=C=v throughout) ----
            f32x4 acc[4];
            #pragma unroll
            for (int s = 0; s < 4; ++s)
                asm("s_nop 2\n\t"
                    "v_mfma_f32_16x16x32_f16 %0, %1, %2, %3"
                    : "=&v"(acc[s])
                    : "v"(Af8[s]), "v"(b9u), "v"(zq));
            #pragma unroll
            for (int kk = 0; kk < 7; ++kk)
                #pragma unroll
                for (int s = 0; s < 4; ++s)
                    asm("v_mfma_f32_16x16x32_f16 %0, %1, %2, %0"
                        : "+v"(acc[s])
                        : "a"(AfA[s][kk]), "v"(bfu[kk]));
            #pragma unroll
            for (int s = 0; s < 4; ++s)
                asm("v_mfma_f32_16x16x32_f16 %0, %1, %2, %0\n\t"
                    "s_nop 7\n\t"
                    "s_nop 1"
                    : "+v"(acc[s])
                    : "a"(AfA[s][7]), "v"(bfu[7]));

            // tanh (D layout: row = quad*4 + r, col = n)
            float hf[4][4];
            #pragma unroll
            for (int s = 0; s < 4; ++s)
                #pragma unroll
                for (int r = 0; r < 4; ++r)
                    hf[s][r] = fast_tanh(acc[s][r]);

            // write h_new as next step's B-fragments (one b64 per subtile)
            #pragma unroll
            for (int s = 0; s < 4; ++s) {
                const int kst = 2 * w + (s >> 1);
                const int q   = 2 * (s & 1) + (qD >> 1);
                uint2* bw = (uint2*)&Bb[wb][kst][q * 16 + n];
                bw[qD & 1] = make_uint2(pk(hf[s][0], hf[s][1]),
                                        pk(hf[s][2], hf[s][3]));
            }

            // head partials (f32 h, pre-quantization — as in R13)
            float p0 = 0.f, p1 = 0.f;
            #pragma unroll
            for (int s = 0; s < 4; ++s)
                #pragma unroll
                for (int r = 0; r < 4; ++r) {
                    p0 = fmaf(wf0[s * 4 + r], hf[s][r], p0);
                    p1 = fmaf(wf1[s * 4 + r], hf[s][r], p1);
                }
            p0 += __shfl_xor(p0, 16, 64);  p0 += __shfl_xor(p0, 32, 64);
            p1 += __shfl_xor(p1, 16, 64);  p1 += __shfl_xor(p1, 32, 64);
            float* h0a = is_q0 ? &Hp[rb][n][w]      : &Dump[l];
            float* h1a = is_q0 ? &Hp[rb][16 + n][w] : &Dump[l];
            *h0a = p0;
            *h1a = p1;

            __syncthreads();
        }

        // finalize step 31 (Hp parity of step 31 is 1)
        if (w == 0 && l < 32) {
            f32x4 h4 = *(const f32x4*)&Hp[1][l][0];
            float o  = h4.x + h4.y + h4.z + h4.w + ((l >> 4) ? bf1 : bf0);
            Obx[CHUNK - 1][l] = fast_tanh(o);
        }
        __syncthreads();

        // flush outputs: element c = n*2+o -> Obx col on = (c&1)*16 + (c>>1)
        for (int e = t; e < CHUNK * 32; e += 256) {
            const int i = e >> 5, c = e & 31;
            const int on = (c & 1) * 16 + (c >> 1);
            out[(size_t)(chunk * CHUNK + i) * BATCH * OUTD + b0 * OUTD + c] =
                Obx[i][on];
        }
    }
}

extern "C" void kernel_launch(void* const* d_in, const int* in_sizes, int n_in,
                              void* d_out, int out_size, void* d_ws, size_t ws_size,
                              hipStream_t stream) {
    const float* input = (const float*)d_in[0];
    // d_in[1] = target (unused by forward)
    const float* Wi = (const float*)d_in[2];
    const float* bi = (const float*)d_in[3];
    const float* Wh = (const float*)d_in[4];
    const float* bh = (const float*)d_in[5];
    const float* Wf = (const float*)d_in[6];
    const float* bf = (const float*)d_in[7];
    float* out = (float*)d_out;

    elman_kernel<<<dim3(BATCH / NB), dim3(256), 0, stream>>>(
        input, Wi, bi, Wh, bh, Wf, bf, out);
}

// Round 17
// 2293.098 us; speedup vs baseline: 1.7487x; 1.7487x over previous
//
#include <hip/hip_runtime.h>

#define T_STEPS 4096
#define BATCH   64
#define INDIM   4
#define H       256
#define OUTD    2
#define CHUNK   32
#define SLOT_DW 36                    // dwords per k-quarter: 32 + 4 skew
#define ENT_DW  (4*SLOT_DW)           // 144 dwords per stored h vector
#define ENT_B   (4*ENT_DW)            // 576 bytes
#define RING_DW (CHUNK*ENT_DW)        // 4608 dwords (18 KB)
#define DUMP_DW 256                   // 1 KB dump for non-writer lanes
#define WF_DW   (OUTD*(H/2))          // 256 dwords packed Wf
#define XS_DW   (CHUNK*INDIM)         // 128 dwords: staged x for the chunk

typedef __fp16 half2v __attribute__((ext_vector_type(2)));

__device__ __forceinline__ float fast_tanh(float x) {
    float ax = fabsf(x);
    float e  = __expf(-2.0f * ax);
    float r  = (1.0f - e) * __builtin_amdgcn_rcpf(1.0f + e);
    return copysignf(r, x);
}

template<int CTRL>
__device__ __forceinline__ float dpp_radd(float a) {
    int s = __builtin_amdgcn_update_dpp(0, __builtin_bit_cast(int, a),
                                        CTRL, 0xf, 0xf, true);
    return a + __builtin_bit_cast(float, s);
}
#define SHL1 0x101
#define SHL2 0x102
#define SHL4 0x104
#define SHR1 0x111
#define SHR2 0x112

// FINAL: measured optimum of the session (R12: 2290 us, 1320 cyc/step).
// 512 thr = 8 waves = 2/SIMD; thread owns 2 rows x 64 k packed-f16 weights
// (resident at VGPR=88); Ksplit=4 with DPP reduce; h ring in LDS (f16,
// bank-derotated); x staged per chunk (VMEM-free step loop); deferred
// output head per chunk. Structures tried and beaten by this one:
// 1024-thr variants (allocator caps at ~52 VGPR -> weight remat),
// R=4 resharding (DPP overhead > LDS saving), pk_fma (same issue rate as
// dot2), MFMA 16-batch GEMM (4 CUs + 1 wave/SIMD latency exposure).
__global__ __attribute__((amdgpu_waves_per_eu(2, 2))) __launch_bounds__(512)
void elman_kernel(const float* __restrict__ input,
                  const float* __restrict__ Wi,
                  const float* __restrict__ bi,
                  const float* __restrict__ Wh,
                  const float* __restrict__ bh,
                  const float* __restrict__ Wf,
                  const float* __restrict__ bf,
                  float* __restrict__ out)
{
    const int b  = blockIdx.x;
    const int t  = threadIdx.x;
    const int rp = t >> 2;        // row pair 0..127
    const int ko = t & 3;         // k-quarter
    const int r0 = rp * 2, r1 = r0 + 1;
    const int k0 = ko * 64;

    __shared__ unsigned int lds[RING_DW + DUMP_DW + WF_DW + XS_DW];
    unsigned int* ring   = lds;
    unsigned int* wf_pk  = lds + RING_DW + DUMP_DW;
    float*        xstage = (float*)(lds + RING_DW + DUMP_DW + WF_DW);

    // --- weights: 2 rows x 64 k packed f16 -> 64 dwords (resident) ---
    half2v w0[32], w1[32];
    {
        const float* p0 = Wh + (size_t)r0 * H + k0;
        const float* p1 = Wh + (size_t)r1 * H + k0;
        #pragma unroll
        for (int j = 0; j < 16; ++j) {
            float4 a = *(const float4*)(p0 + 4 * j);
            float4 c = *(const float4*)(p1 + 4 * j);
            w0[2 * j]     = __builtin_amdgcn_cvt_pkrtz(a.x, a.y);
            w0[2 * j + 1] = __builtin_amdgcn_cvt_pkrtz(a.z, a.w);
            w1[2 * j]     = __builtin_amdgcn_cvt_pkrtz(c.x, c.y);
            w1[2 * j + 1] = __builtin_amdgcn_cvt_pkrtz(c.z, c.w);
        }
    }
    #pragma unroll
    for (int j = 0; j < 32; ++j) {
        float f0 = __builtin_bit_cast(float, w0[j]);
        float f1 = __builtin_bit_cast(float, w1[j]);
        asm volatile("" : "+v"(f0), "+v"(f1));
        w0[j] = __builtin_bit_cast(half2v, f0);
        w1[j] = __builtin_bit_cast(half2v, f1);
    }

    // epilogue role: lane ko==0 finalizes row r0, lane ko==3 finalizes row r1
    const int  ko3      = (ko == 3);
    const int  row_mine = r0 + ko3;
    const int  is_wr    = (ko == 0) | ko3;
    const float4 wim    = *(const float4*)(Wi + row_mine * INDIM);
    const float  biasm  = bi[row_mine] + bh[row_mine];
    const float  bf0    = bf[0], bf1 = bf[1];
    const int  boff     = (row_mine >> 6) * (SLOT_DW * 4) + (row_mine & 63) * 2;
    const int  dumpoff  = RING_DW * 4 + t * 2;

    if (t < WF_DW) {
        const int o = t >> 7, e = t & 127;
        wf_pk[t] = __builtin_bit_cast(unsigned int,
            __builtin_amdgcn_cvt_pkrtz(Wf[o * H + 2 * e], Wf[o * H + 2 * e + 1]));
    }
    if (t < H / 2) ring[(CHUNK - 1) * ENT_DW + (t >> 5) * SLOT_DW + (t & 31)] = 0u;
    __syncthreads();

    const unsigned int rd_off = (unsigned int)(ko * SLOT_DW);

    for (int chunk = 0; chunk < T_STEPS / CHUNK; ++chunk) {
        // ---- stage this chunk's x into LDS (only VMEM reads per chunk) ----
        if (t < XS_DW) {
            const int s = chunk * CHUNK + (t >> 2);
            xstage[t] = input[((size_t)s * BATCH + b) * INDIM + (t & 3)];
        }
        __syncthreads();

        #pragma unroll 1
        for (int i = 0; i < CHUNK; ++i) {
            const unsigned int* hb =
                ring + ((i + CHUNK - 1) & (CHUNK - 1)) * ENT_DW + rd_off;
            uint4 hv[8];
            #pragma unroll
            for (int j = 0; j < 8; ++j) hv[j] = *(const uint4*)(hb + 4 * j);
            const float4 xs = *(const float4*)(xstage + 4 * i);

            float acc0 = 0.f, acc1 = 0.f;
            #pragma unroll
            for (int j = 0; j < 8; ++j) {
                half2v h0 = __builtin_bit_cast(half2v, hv[j].x);
                half2v h1 = __builtin_bit_cast(half2v, hv[j].y);
                half2v h2 = __builtin_bit_cast(half2v, hv[j].z);
                half2v h3 = __builtin_bit_cast(half2v, hv[j].w);
                acc0 = __builtin_amdgcn_fdot2(w0[4 * j],     h0, acc0, false);
                acc1 = __builtin_amdgcn_fdot2(w1[4 * j],     h0, acc1, false);
                acc0 = __builtin_amdgcn_fdot2(w0[4 * j + 1], h1, acc0, false);
                acc1 = __builtin_amdgcn_fdot2(w1[4 * j + 1], h1, acc1, false);
                acc0 = __builtin_amdgcn_fdot2(w0[4 * j + 2], h2, acc0, false);
                acc1 = __builtin_amdgcn_fdot2(w1[4 * j + 2], h2, acc1, false);
                acc0 = __builtin_amdgcn_fdot2(w0[4 * j + 3], h3, acc0, false);
                acc1 = __builtin_amdgcn_fdot2(w1[4 * j + 3], h3, acc1, false);
            }

            // DPP reduce over the 4-lane group: acc0 -> lane 0, acc1 -> lane 3
            acc0 = dpp_radd<SHL2>(acc0);
            acc0 = dpp_radd<SHL1>(acc0);
            acc1 = dpp_radd<SHR2>(acc1);
            acc1 = dpp_radd<SHR1>(acc1);

            // unmasked epilogue: every lane finalizes one row (2 of 4 valid)
            float accm = ko3 ? acc1 : acc0;
            float pre  = accm + biasm +
                xs.x * wim.x + xs.y * wim.y + xs.z * wim.z + xs.w * wim.w;
            __fp16 h16 = (__fp16)fast_tanh(pre);
            int waddr  = is_wr ? (i * ENT_B + boff) : dumpoff;
            *(__fp16*)((char*)lds + waddr) = h16;

            __syncthreads();
        }

        // --- deferred output head: 64 tasks x 8 lanes ---
        {
            const int task = t >> 3;
            const int s    = task >> 1;
            const int o    = task & 1;
            const int sub  = t & 7;
            const unsigned int* hp =
                ring + s * ENT_DW + (sub >> 1) * SLOT_DW + (sub & 1) * 16;
            const unsigned int* wp = wf_pk + o * (H / 2) + sub * 16;

            uint4 hA = *(const uint4*)(hp);
            uint4 hB = *(const uint4*)(hp + 4);
            uint4 hC = *(const uint4*)(hp + 8);
            uint4 hD = *(const uint4*)(hp + 12);
            uint4 wA = *(const uint4*)(wp);
            uint4 wB = *(const uint4*)(wp + 4);
            uint4 wC = *(const uint4*)(wp + 8);
            uint4 wD = *(const uint4*)(wp + 12);
            unsigned int hh[16] = {hA.x, hA.y, hA.z, hA.w, hB.x, hB.y, hB.z, hB.w,
                                   hC.x, hC.y, hC.z, hC.w, hD.x, hD.y, hD.z, hD.w};
            unsigned int ww[16] = {wA.x, wA.y, wA.z, wA.w, wB.x, wB.y, wB.z, wB.w,
                                   wC.x, wC.y, wC.z, wC.w, wD.x, wD.y, wD.z, wD.w};

            float acc = 0.f;
            #pragma unroll
            for (int j = 0; j < 16; ++j)
                acc = __builtin_amdgcn_fdot2(__builtin_bit_cast(half2v, ww[j]),
                                             __builtin_bit_cast(half2v, hh[j]),
                                             acc, false);
            acc = dpp_radd<SHL4>(acc);
            acc = dpp_radd<SHL2>(acc);
            acc = dpp_radd<SHL1>(acc);

            if (sub == 0) {
                out[((size_t)(chunk * CHUNK + s) * BATCH + b) * OUTD + o] =
                    fast_tanh(acc + (o ? bf1 : bf0));
            }
            __syncthreads();
        }
    }
}

extern "C" void kernel_launch(void* const* d_in, const int* in_sizes, int n_in,
                              void* d_out, int out_size, void* d_ws, size_t ws_size,
                              hipStream_t stream) {
    const float* input = (const float*)d_in[0];
    // d_in[1] = target (unused by forward)
    const float* Wi = (const float*)d_in[2];
    const float* bi = (const float*)d_in[3];
    const float* Wh = (const float*)d_in[4];
    const float* bh = (const float*)d_in[5];
    const float* Wf = (const float*)d_in[6];
    const float* bf = (const float*)d_in[7];
    float* out = (float*)d_out;

    elman_kernel<<<dim3(BATCH), dim3(512), 0, stream>>>(
        input, Wi, bi, Wh, bh, Wf, bf, out);
}